// Round 5
// baseline (4415.405 us; speedup 1.0000x reference)
//
#include <hip/hip_runtime.h>
#include <stdint.h>

// Seq_CNN_Big_Attention: qkv 1x5 conv (reflect pad) -> flash attn (head dim 512)
// -> 8x5 out conv. bf16 MFMA pipeline, per-batch sequential to bound ws.
// R5: k_attn rewritten: 4 waves x 32 q-rows, 32x32x16 MFMA, swapped QK^T
//     (S^T = K·Q^T) + cvt_pk/permlane32_swap in-register P (no P LDS trip),
//     conflict-free K/V LDS swizzles. Halves LDS traffic vs R4.
// Workspace (needs 136.2 MB):
//   [0,32M)    Qg bf16 [8][4096][512]  (f = d*8+m, pre-scaled 0.125*log2e)
//   [32M,64M)  Kg bf16 [8][4096][512]
//   [64M,96M)  Vg bf16 [8][512][4096]  (transposed for PV B-frags)
//   [96M,128M) AO bf16 [4096][4096]    (feat = ic*8+mi)
//   [128M,130M) WB1 bf16 [1536][640]   (qkv weights, k = t*128+ci)
//   WB2 bf16 [1024][20480] overlays Qg/Kg during k_outconv (reconverted per b)

typedef __attribute__((ext_vector_type(8))) short short8;
typedef __attribute__((ext_vector_type(4))) short short4v;
typedef __attribute__((ext_vector_type(2))) short short2v;
typedef __attribute__((ext_vector_type(4))) float f32x4;
typedef __attribute__((ext_vector_type(16))) float f32x16;

__device__ __forceinline__ f32x4 mfma16(short8 a, short8 b, f32x4 c) {
  return __builtin_amdgcn_mfma_f32_16x16x32_bf16(a, b, c, 0, 0, 0);
}
__device__ __forceinline__ f32x16 mfma32(short8 a, short8 b, f32x16 c) {
  return __builtin_amdgcn_mfma_f32_32x32x16_bf16(a, b, c, 0, 0, 0);
}

__device__ __forceinline__ unsigned short f2bf(float f) {  // RNE f32->bf16
  union { float f; uint32_t u; } v; v.f = f;
  uint32_t r = (v.u + 0x7fffu + ((v.u >> 16) & 1u)) >> 16;
  return (unsigned short)r;
}

__device__ __forceinline__ uint32_t cvtpk(float lo, float hi) {
  uint32_t r;
  asm volatile("v_cvt_pk_bf16_f32 %0, %1, %2" : "=v"(r) : "v"(lo), "v"(hi));
  return r;
}
__device__ __forceinline__ void plswap(uint32_t& a, uint32_t& b) {
  // a.lanes[32:63] <-> b.lanes[0:31]
  asm volatile("v_permlane32_swap_b32 %0, %1" : "+v"(a), "+v"(b));
}

__device__ __forceinline__ int refl4096(int p) {  // reflect pad-2 index
  p = p < 0 ? -p : p;
  return p >= 4096 ? 8190 - p : p;
}

__device__ __forceinline__ void gl_lds16(const void* g, void* l) {
  __builtin_amdgcn_global_load_lds(
      (const __attribute__((address_space(1))) void*)g,
      (__attribute__((address_space(3))) void*)l, 16, 0, 0);
}

// ---------------- weight converters ----------------
__global__ void k_convw_qkv(const float* __restrict__ Wq,
                            const float* __restrict__ Wkv,
                            unsigned short* __restrict__ out) {
  int e = blockIdx.x * 256 + threadIdx.x;  // 1536*640 exact
  int oc = e / 640, k = e - oc * 640;
  int ci = k & 127, t = k >> 7;
  float w = (oc < 512) ? Wq[oc * 640 + ci * 5 + t]
                       : Wkv[(oc - 512) * 640 + ci * 5 + t];
  out[e] = f2bf(w);
}

// one block per oc row: coalesced f32x4 read -> LDS bf16 -> coalesced write
__global__ __launch_bounds__(256)
void k_convw_out(const float* __restrict__ Wout,
                 unsigned short* __restrict__ out) {
  __shared__ unsigned short row_l[20480];
  const int oc = blockIdx.x;
  const int tid = threadIdx.x;
  const float* src = Wout + (size_t)oc * 20480;
#pragma unroll
  for (int i0 = 0; i0 < 5120; i0 += 256) {  // 20 rounds of f32x4
    int i = i0 + tid;
    f32x4 v = *(const f32x4*)(src + (size_t)i * 4);
    short4v pk;
    pk[0] = (short)f2bf(v[0]); pk[1] = (short)f2bf(v[1]);
    pk[2] = (short)f2bf(v[2]); pk[3] = (short)f2bf(v[3]);
    *(short4v*)(row_l + i * 4) = pk;
  }
  __syncthreads();
  unsigned short* drow = out + (size_t)oc * 20480;
#pragma unroll
  for (int r0 = 0; r0 < 20480; r0 += 512) {  // 40 rounds of ushort2
    int e = r0 + tid * 2;
    int t0 = e >> 12, ft0 = e & 4095;
    int t1 = (e + 1) >> 12, ft1 = (e + 1) & 4095;
    short2v pk;
    pk[0] = (short)row_l[(ft0 >> 3) * 40 + (ft0 & 7) * 5 + t0];
    pk[1] = (short)row_l[(ft1 >> 3) * 40 + (ft1 & 7) * 5 + t1];
    *(short2v*)(drow + e) = pk;
  }
}

// ---------------- K1: qkv conv as GEMM (M=128pos x N=128oc, K=640) ----------------
__global__ __launch_bounds__(256, 2)
void k_qkv(const float* __restrict__ x, const unsigned short* __restrict__ Wb,
           unsigned short* __restrict__ Qg, unsigned short* __restrict__ Kg,
           unsigned short* __restrict__ Vg, int b) {
  __shared__ __align__(16) unsigned short As[128 * 64];
  __shared__ __align__(16) unsigned short Bs[128 * 64];
  const int tid = threadIdx.x;
  const int lane = tid & 63, w = tid >> 6;
  const int wr = w >> 1, wc = w & 1;
  const int l15 = lane & 15, lg = lane >> 4;
  const int p0 = blockIdx.x * 128;
  const int ocb = blockIdx.y * 128;
  const int m = blockIdx.z;

  f32x4 acc[4][4];
#pragma unroll
  for (int i = 0; i < 4; i++)
#pragma unroll
    for (int j = 0; j < 4; j++) acc[i][j] = (f32x4){0.f, 0.f, 0.f, 0.f};

  for (int ks = 0; ks < 10; ks++) {
    const int t = ks >> 1;
    const int ci0 = (ks & 1) << 6;
    __syncthreads();
    // stage A: im2col 128 pos x 64 ci, f32->bf16, 16B chunks swizzled c^=row&7
#pragma unroll
    for (int rr = 0; rr < 8; rr++) {
      int slot = tid + (rr << 8);
      int row = slot >> 4, c4 = slot & 15;
      int xn = refl4096(p0 + row - 2 + t);
      const f32x4 v = *(const f32x4*)(x + ((size_t)b * 4096 + xn) * 1024 +
                                      m * 128 + ci0 + (c4 << 2));
      short4v pk;
      pk[0] = (short)f2bf(v[0]); pk[1] = (short)f2bf(v[1]);
      pk[2] = (short)f2bf(v[2]); pk[3] = (short)f2bf(v[3]);
      int byte = (row << 7) + ((((c4 >> 1) ^ (row & 7))) << 4) + ((c4 & 1) << 3);
      *(short4v*)((char*)As + byte) = pk;
    }
    // stage B: bf16 weights straight to LDS (inverse-swizzled source)
#pragma unroll
    for (int c = 0; c < 4; c++) {
      int sb = ((c << 2) + w) << 6;
      int slot = sb + lane;
      int row = slot >> 3, cc = slot & 7;
      int cs = cc ^ (row & 7);
      gl_lds16(Wb + (size_t)(ocb + row) * 640 + (ks << 6) + (cs << 3),
               (char*)Bs + (size_t)sb * 16);
    }
    __syncthreads();
#pragma unroll
    for (int kk = 0; kk < 2; kk++) {
      short8 af[4], bq[4];
#pragma unroll
      for (int i = 0; i < 4; i++) {
        int row = (wr << 6) + (i << 4) + l15;
        af[i] = *(const short8*)((char*)As + (row << 7) +
                                 ((((kk << 2) + lg) ^ (row & 7)) << 4));
      }
#pragma unroll
      for (int j = 0; j < 4; j++) {
        int row = (wc << 6) + (j << 4) + l15;
        bq[j] = *(const short8*)((char*)Bs + (row << 7) +
                                 ((((kk << 2) + lg) ^ (row & 7)) << 4));
      }
#pragma unroll
      for (int i = 0; i < 4; i++)
#pragma unroll
        for (int j = 0; j < 4; j++) acc[i][j] = mfma16(af[i], bq[j], acc[i][j]);
    }
  }

  const int region = ocb >> 9;  // 0:Q 1:K 2:V
  // Q pre-scale: 1/sqrt(64) * log2(e) so attn P = exp2(S) directly
  const float QSCALE = 0.18033688f;
#pragma unroll
  for (int i = 0; i < 4; i++) {
    const int posb = p0 + (wr << 6) + (i << 4) + (lg << 2);
#pragma unroll
    for (int j = 0; j < 4; j++) {
      const int oc = ocb + (wc << 6) + (j << 4) + l15;
      const int ocr = oc & 511;
      const int hh = ocr >> 6, dd = ocr & 63;
      const int f = (dd << 3) + m;
      if (region == 0) {
        size_t base = (size_t)hh * 4096 * 512 + f;
#pragma unroll
        for (int r = 0; r < 4; r++)
          Qg[base + (size_t)(posb + r) * 512] = f2bf(acc[i][j][r] * QSCALE);
      } else if (region == 1) {
        size_t base = (size_t)hh * 4096 * 512 + f;
#pragma unroll
        for (int r = 0; r < 4; r++)
          Kg[base + (size_t)(posb + r) * 512] = f2bf(acc[i][j][r]);
      } else {
        short4v pk;
#pragma unroll
        for (int r = 0; r < 4; r++) pk[r] = (short)f2bf(acc[i][j][r]);
        *(short4v*)(Vg + ((size_t)hh * 512 + f) * 4096 + posb) = pk;
      }
    }
  }
}

// ---------------- K2: flash attention, 4 waves x 32 q-rows, KBLK=32 ----------------
// 32x32x16 MFMA. Swapped QK^T: S^T = mfma(A=K, B=Q) -> lane's col = q (lane&31),
// rows = keys in regs. P stays in registers: cvt_pk pairs + permlane32_swap
// build the PV A-frags (lane: P[q=lane&31][8 keys]). Fixed-reference softmax
// (P = exp2(S), log2e folded into Q), l via in-register key-sum + one shfl.
// LDS: K tile [32 key][64 x 16B], chunk c holds f-chunk (c ^ key)  (8-pass reads)
//      V^T tile [256 rows=2f][8 x 16B], chunk c holds cu = c ^ (row&7),
//        cu: f_lsb = cu>>2, key-offset = (cu&3)*8                  (8-pass reads)
__global__ __launch_bounds__(256, 1)
void k_attn(const unsigned short* __restrict__ Qg,
            const unsigned short* __restrict__ Kg,
            const unsigned short* __restrict__ Vg,
            unsigned short* __restrict__ AO) {
  __shared__ __align__(16) char lds[65536 + 512];
  char* Kt = lds;
  char* Vt = lds + 32768;
  float* Ls = (float*)(lds + 65536);  // [4 waves][32 q] row sums

  const int tid = threadIdx.x;
  const int lane = tid & 63, w = tid >> 6;
  const int l31 = lane & 31, hi = lane >> 5;
  const int h = blockIdx.y;
  const int qbase = blockIdx.x * 128 + w * 32;

  const size_t kb = (size_t)h * 4096 * 512;
  const size_t vb = (size_t)h * 512 * 4096;

  // Q B-frags: lane holds Q[q = qbase+l31][f = ks*16 + hi*8 + j]
  short8 q[32];
  {
    const unsigned short* qp =
        Qg + ((size_t)h * 4096 + qbase + l31) * 512 + hi * 8;
#pragma unroll
    for (int ks = 0; ks < 32; ks++) q[ks] = *(const short8*)(qp + ks * 16);
  }

  f32x16 o[16];
#pragma unroll
  for (int t = 0; t < 16; t++)
#pragma unroll
    for (int e = 0; e < 16; e++) o[t][e] = 0.f;
  float lacc = 0.f;

  // PV read constants
  const int rb = l31 >> 1;
  const int swz = rb & 7;
  const int cg0 = ((l31 & 1) << 2) + hi;
  const int voff1 = rb * 128 + ((cg0 ^ swz) << 4);
  const int voff2 = rb * 128 + (((cg0 + 2) ^ swz) << 4);

  union U { uint32_t d[4]; short8 s; };

  for (int it = 0; it < 128; it++) {
    const int key0 = it << 5;
    __syncthreads();
#pragma unroll
    for (int i = 0; i < 8; i++) {  // K tile: 2048 16B slots
      int s = tid + (i << 8);
      int r = s >> 6, c = s & 63;
      gl_lds16(Kg + kb + (size_t)(key0 + r) * 512 + ((c ^ r) << 3),
               Kt + (size_t)s * 16);
    }
#pragma unroll
    for (int i = 0; i < 8; i++) {  // V^T tile: 2048 16B slots
      int s = tid + (i << 8);
      int rp = s >> 3, c = s & 7;
      int cu = c ^ (rp & 7);
      int f = (rp << 1) + (cu >> 2);
      gl_lds16(Vg + vb + (size_t)f * 4096 + key0 + ((cu & 3) << 3),
               Vt + (size_t)s * 16);
    }
    __syncthreads();

    // S^T = K · Q^T  (32 keys x 32 q), contraction over f = 512
    f32x16 st;
#pragma unroll
    for (int e = 0; e < 16; e++) st[e] = 0.f;
#pragma unroll
    for (int ks = 0; ks < 32; ks++) {
      short8 kfrag = *(const short8*)(
          Kt + (l31 << 10) + ((((ks << 1) + hi) ^ l31) << 4));
      st = mfma32(kfrag, q[ks], st);
    }

    // P = exp2(S); lane has P[key=(r&3)+8(r>>2)+4hi][q=l31]
    float p[16];
#pragma unroll
    for (int r = 0; r < 16; r++) p[r] = __builtin_amdgcn_exp2f(st[r]);
    lacc += ((p[0] + p[1]) + (p[2] + p[3])) + ((p[4] + p[5]) + (p[6] + p[7])) +
            (((p[8] + p[9]) + (p[10] + p[11])) +
             ((p[12] + p[13]) + (p[14] + p[15])));

    // pack -> PV A-frags (lane: row=q=l31, k=8*hi+j)
    uint32_t d0 = cvtpk(p[0], p[1]),  d1 = cvtpk(p[2], p[3]);
    uint32_t d2 = cvtpk(p[4], p[5]),  d3 = cvtpk(p[6], p[7]);
    uint32_t d4 = cvtpk(p[8], p[9]),  d5 = cvtpk(p[10], p[11]);
    uint32_t d6 = cvtpk(p[12], p[13]), d7 = cvtpk(p[14], p[15]);
    plswap(d0, d2); plswap(d1, d3);  // frag1: keys 0..15
    plswap(d4, d6); plswap(d5, d7);  // frag2: keys 16..31
    U u1; u1.d[0] = d0; u1.d[1] = d1; u1.d[2] = d2; u1.d[3] = d3;
    U u2; u2.d[0] = d4; u2.d[1] = d5; u2.d[2] = d6; u2.d[3] = d7;

    // O += P · V  (16 f-tiles x 2 key-frags)
#pragma unroll
    for (int t = 0; t < 16; t++) {
      const char* vrow = Vt + t * 2048;
      short8 v1 = *(const short8*)(vrow + voff1);
      short8 v2 = *(const short8*)(vrow + voff2);
      o[t] = mfma32(u1.s, v1, o[t]);
      o[t] = mfma32(u2.s, v2, o[t]);
    }
  }

  lacc += __shfl_xor(lacc, 32, 64);
  Ls[(w << 5) + l31] = lacc;  // lanes l and l+32 write same value: benign
  __syncthreads();

  float linv[16];
#pragma unroll
  for (int r = 0; r < 16; r++) {
    int qq = (r & 3) + ((r >> 2) << 3) + (hi << 2);
    linv[r] = 1.f / Ls[(w << 5) + qq];
  }
#pragma unroll
  for (int t = 0; t < 16; t++) {
    size_t col = (size_t)h * 512 + (t << 5) + l31;
#pragma unroll
    for (int r = 0; r < 16; r++) {
      int qq = qbase + (r & 3) + ((r >> 2) << 3) + (hi << 2);
      AO[(size_t)qq * 4096 + col] = f2bf(o[t][r] * linv[r]);
    }
  }
}

// ---------------- K3: out conv as GEMM (M=128pos x N=128oc, K=20480) ----------------
__global__ __launch_bounds__(256, 2)
void k_outconv(const unsigned short* __restrict__ AO,
               const unsigned short* __restrict__ WB,
               float* __restrict__ outp, int b) {
  __shared__ __align__(16) unsigned short As[128 * 64];
  __shared__ __align__(16) unsigned short Bs[128 * 64];
  const int tid = threadIdx.x;
  const int lane = tid & 63, w = tid >> 6;
  const int wr = w >> 1, wc = w & 1;
  const int l15 = lane & 15, lg = lane >> 4;
  const int i0 = blockIdx.x * 128;
  const int ocb = blockIdx.y * 128;

  f32x4 acc[4][4];
#pragma unroll
  for (int i = 0; i < 4; i++)
#pragma unroll
    for (int j = 0; j < 4; j++) acc[i][j] = (f32x4){0.f, 0.f, 0.f, 0.f};

  for (int ks = 0; ks < 320; ks++) {
    const int k0 = ks << 6;
    const int t = k0 >> 12;
    const int f0 = k0 & 4095;
    __syncthreads();
#pragma unroll
    for (int c = 0; c < 4; c++) {  // A: att_out rows with reflect shift
      int sb = ((c << 2) + w) << 6;
      int slot = sb + lane;
      int row = slot >> 3, cc = slot & 7;
      int cs = cc ^ (row & 7);
      int sr = refl4096(i0 + row + t - 2);
      gl_lds16(AO + (size_t)sr * 4096 + f0 + (cs << 3),
               (char*)As + (size_t)sb * 16);
    }
#pragma unroll
    for (int c = 0; c < 4; c++) {  // B: Wout bf16 k-major
      int sb = ((c << 2) + w) << 6;
      int slot = sb + lane;
      int row = slot >> 3, cc = slot & 7;
      int cs = cc ^ (row & 7);
      gl_lds16(WB + (size_t)(ocb + row) * 20480 + k0 + (cs << 3),
               (char*)Bs + (size_t)sb * 16);
    }
    __syncthreads();
#pragma unroll
    for (int kk = 0; kk < 2; kk++) {
      short8 af[4], bq[4];
#pragma unroll
      for (int i = 0; i < 4; i++) {
        int row = (wr << 6) + (i << 4) + l15;
        af[i] = *(const short8*)((char*)As + (row << 7) +
                                 ((((kk << 2) + lg) ^ (row & 7)) << 4));
      }
#pragma unroll
      for (int j = 0; j < 4; j++) {
        int row = (wc << 6) + (j << 4) + l15;
        bq[j] = *(const short8*)((char*)Bs + (row << 7) +
                                 ((((kk << 2) + lg) ^ (row & 7)) << 4));
      }
#pragma unroll
      for (int i = 0; i < 4; i++)
#pragma unroll
        for (int j = 0; j < 4; j++) acc[i][j] = mfma16(af[i], bq[j], acc[i][j]);
    }
  }
#pragma unroll
  for (int i = 0; i < 4; i++)
#pragma unroll
    for (int j = 0; j < 4; j++) {
      int oc = ocb + (wc << 6) + (j << 4) + l15;
      int pos = i0 + (wr << 6) + (i << 4) + (lg << 2);
      *(f32x4*)(outp + ((size_t)b * 1024 + oc) * 4096 + pos) = acc[i][j];
    }
}

// ---------------- launch ----------------
extern "C" void kernel_launch(void* const* d_in, const int* in_sizes, int n_in,
                              void* d_out, int out_size, void* d_ws,
                              size_t ws_size, hipStream_t stream) {
  const float* x = (const float*)d_in[0];
  const float* Wq = (const float*)d_in[1];
  const float* Wkv = (const float*)d_in[2];
  const float* Wout = (const float*)d_in[3];
  float* out = (float*)d_out;
  char* ws = (char*)d_ws;

  const size_t SEG = 33554432;  // 32 MiB
  unsigned short* Qg = (unsigned short*)ws;
  unsigned short* Kg = (unsigned short*)(ws + SEG);
  unsigned short* Vg = (unsigned short*)(ws + 2 * SEG);
  unsigned short* AO = (unsigned short*)(ws + 3 * SEG);
  unsigned short* WB1 = (unsigned short*)(ws + 4 * SEG);  // 1.97 MB
  unsigned short* WB2 = (unsigned short*)ws;  // overlays Qg/Kg during k_outconv

  k_convw_qkv<<<3840, 256, 0, stream>>>(Wq, Wkv, WB1);
  for (int b = 0; b < 2; b++) {
    k_qkv<<<dim3(32, 12, 8), 256, 0, stream>>>(x, WB1, Qg, Kg, Vg, b);
    k_attn<<<dim3(32, 8), 256, 0, stream>>>(Qg, Kg, Vg, AO);
    k_convw_out<<<1024, 256, 0, stream>>>(Wout, WB2);
    k_outconv<<<dim3(32, 8), 256, 0, stream>>>(AO, WB2, out, b);
  }
}

// Round 6
// 1668.800 us; speedup vs baseline: 2.6459x; 2.6459x over previous
//
#include <hip/hip_runtime.h>
#include <stdint.h>

// Seq_CNN_Big_Attention: qkv 1x5 conv (reflect pad) -> flash attn (head dim 512)
// -> 8x5 out conv. bf16 MFMA pipeline, per-batch sequential to bound ws.
// R6: k_attn = R5 math with f-split wave pairs (q[16]+o[8] regs <= 256, 2 w/SIMD,
//     partial-S^T LDS exchange). k_outconv = A-tile staged once, 5 shifted taps.
// Workspace (needs 136.2 MB):
//   [0,32M)    Qg bf16 [8][4096][512]  (f = d*8+m, pre-scaled 0.125*log2e)
//   [32M,64M)  Kg bf16 [8][4096][512]
//   [64M,96M)  Vg bf16 [8][512][4096]  (transposed for PV B-frags)
//   [96M,128M) AO bf16 [4096][4096]    (feat = ic*8+mi)
//   [128M,130M) WB1 bf16 [1536][640]   (qkv weights, k = t*128+ci)
//   WB2 bf16 [1024][20480] overlays Qg/Kg during k_outconv (reconverted per b)

typedef __attribute__((ext_vector_type(8))) short short8;
typedef __attribute__((ext_vector_type(4))) short short4v;
typedef __attribute__((ext_vector_type(2))) short short2v;
typedef __attribute__((ext_vector_type(4))) float f32x4;
typedef __attribute__((ext_vector_type(16))) float f32x16;

__device__ __forceinline__ f32x4 mfma16(short8 a, short8 b, f32x4 c) {
  return __builtin_amdgcn_mfma_f32_16x16x32_bf16(a, b, c, 0, 0, 0);
}
__device__ __forceinline__ f32x16 mfma32(short8 a, short8 b, f32x16 c) {
  return __builtin_amdgcn_mfma_f32_32x32x16_bf16(a, b, c, 0, 0, 0);
}

__device__ __forceinline__ unsigned short f2bf(float f) {  // RNE f32->bf16
  union { float f; uint32_t u; } v; v.f = f;
  uint32_t r = (v.u + 0x7fffu + ((v.u >> 16) & 1u)) >> 16;
  return (unsigned short)r;
}

__device__ __forceinline__ uint32_t cvtpk(float lo, float hi) {
  uint32_t r;
  asm volatile("v_cvt_pk_bf16_f32 %0, %1, %2" : "=v"(r) : "v"(lo), "v"(hi));
  return r;
}
__device__ __forceinline__ void plswap(uint32_t& a, uint32_t& b) {
  asm volatile("v_permlane32_swap_b32 %0, %1" : "+v"(a), "+v"(b));
}

__device__ __forceinline__ int refl4096(int p) {  // reflect pad-2 index
  p = p < 0 ? -p : p;
  return p >= 4096 ? 8190 - p : p;
}

__device__ __forceinline__ void gl_lds16(const void* g, void* l) {
  __builtin_amdgcn_global_load_lds(
      (const __attribute__((address_space(1))) void*)g,
      (__attribute__((address_space(3))) void*)l, 16, 0, 0);
}

// ---------------- weight converters ----------------
__global__ void k_convw_qkv(const float* __restrict__ Wq,
                            const float* __restrict__ Wkv,
                            unsigned short* __restrict__ out) {
  int e = blockIdx.x * 256 + threadIdx.x;  // 1536*640 exact
  int oc = e / 640, k = e - oc * 640;
  int ci = k & 127, t = k >> 7;
  float w = (oc < 512) ? Wq[oc * 640 + ci * 5 + t]
                       : Wkv[(oc - 512) * 640 + ci * 5 + t];
  out[e] = f2bf(w);
}

// one block per oc row: coalesced f32x4 read -> LDS bf16 -> coalesced write
__global__ __launch_bounds__(256)
void k_convw_out(const float* __restrict__ Wout,
                 unsigned short* __restrict__ out) {
  __shared__ unsigned short row_l[20480];
  const int oc = blockIdx.x;
  const int tid = threadIdx.x;
  const float* src = Wout + (size_t)oc * 20480;
#pragma unroll
  for (int i0 = 0; i0 < 5120; i0 += 256) {  // 20 rounds of f32x4
    int i = i0 + tid;
    f32x4 v = *(const f32x4*)(src + (size_t)i * 4);
    short4v pk;
    pk[0] = (short)f2bf(v[0]); pk[1] = (short)f2bf(v[1]);
    pk[2] = (short)f2bf(v[2]); pk[3] = (short)f2bf(v[3]);
    *(short4v*)(row_l + i * 4) = pk;
  }
  __syncthreads();
  unsigned short* drow = out + (size_t)oc * 20480;
#pragma unroll
  for (int r0 = 0; r0 < 20480; r0 += 512) {  // 40 rounds of ushort2
    int e = r0 + tid * 2;
    int t0 = e >> 12, ft0 = e & 4095;
    int t1 = (e + 1) >> 12, ft1 = (e + 1) & 4095;
    short2v pk;
    pk[0] = (short)row_l[(ft0 >> 3) * 40 + (ft0 & 7) * 5 + t0];
    pk[1] = (short)row_l[(ft1 >> 3) * 40 + (ft1 & 7) * 5 + t1];
    *(short2v*)(drow + e) = pk;
  }
}

// ---------------- K1: qkv conv as GEMM (M=128pos x N=128oc, K=640) ----------------
__global__ __launch_bounds__(256, 2)
void k_qkv(const float* __restrict__ x, const unsigned short* __restrict__ Wb,
           unsigned short* __restrict__ Qg, unsigned short* __restrict__ Kg,
           unsigned short* __restrict__ Vg, int b) {
  __shared__ __align__(16) unsigned short As[128 * 64];
  __shared__ __align__(16) unsigned short Bs[128 * 64];
  const int tid = threadIdx.x;
  const int lane = tid & 63, w = tid >> 6;
  const int wr = w >> 1, wc = w & 1;
  const int l15 = lane & 15, lg = lane >> 4;
  const int p0 = blockIdx.x * 128;
  const int ocb = blockIdx.y * 128;
  const int m = blockIdx.z;

  f32x4 acc[4][4];
#pragma unroll
  for (int i = 0; i < 4; i++)
#pragma unroll
    for (int j = 0; j < 4; j++) acc[i][j] = (f32x4){0.f, 0.f, 0.f, 0.f};

  for (int ks = 0; ks < 10; ks++) {
    const int t = ks >> 1;
    const int ci0 = (ks & 1) << 6;
    __syncthreads();
#pragma unroll
    for (int rr = 0; rr < 8; rr++) {
      int slot = tid + (rr << 8);
      int row = slot >> 4, c4 = slot & 15;
      int xn = refl4096(p0 + row - 2 + t);
      const f32x4 v = *(const f32x4*)(x + ((size_t)b * 4096 + xn) * 1024 +
                                      m * 128 + ci0 + (c4 << 2));
      short4v pk;
      pk[0] = (short)f2bf(v[0]); pk[1] = (short)f2bf(v[1]);
      pk[2] = (short)f2bf(v[2]); pk[3] = (short)f2bf(v[3]);
      int byte = (row << 7) + ((((c4 >> 1) ^ (row & 7))) << 4) + ((c4 & 1) << 3);
      *(short4v*)((char*)As + byte) = pk;
    }
#pragma unroll
    for (int c = 0; c < 4; c++) {
      int sb = ((c << 2) + w) << 6;
      int slot = sb + lane;
      int row = slot >> 3, cc = slot & 7;
      int cs = cc ^ (row & 7);
      gl_lds16(Wb + (size_t)(ocb + row) * 640 + (ks << 6) + (cs << 3),
               (char*)Bs + (size_t)sb * 16);
    }
    __syncthreads();
#pragma unroll
    for (int kk = 0; kk < 2; kk++) {
      short8 af[4], bq[4];
#pragma unroll
      for (int i = 0; i < 4; i++) {
        int row = (wr << 6) + (i << 4) + l15;
        af[i] = *(const short8*)((char*)As + (row << 7) +
                                 ((((kk << 2) + lg) ^ (row & 7)) << 4));
      }
#pragma unroll
      for (int j = 0; j < 4; j++) {
        int row = (wc << 6) + (j << 4) + l15;
        bq[j] = *(const short8*)((char*)Bs + (row << 7) +
                                 ((((kk << 2) + lg) ^ (row & 7)) << 4));
      }
#pragma unroll
      for (int i = 0; i < 4; i++)
#pragma unroll
        for (int j = 0; j < 4; j++) acc[i][j] = mfma16(af[i], bq[j], acc[i][j]);
    }
  }

  const int region = ocb >> 9;  // 0:Q 1:K 2:V
  const float QSCALE = 0.18033688f;  // 1/8 * log2(e)
#pragma unroll
  for (int i = 0; i < 4; i++) {
    const int posb = p0 + (wr << 6) + (i << 4) + (lg << 2);
#pragma unroll
    for (int j = 0; j < 4; j++) {
      const int oc = ocb + (wc << 6) + (j << 4) + l15;
      const int ocr = oc & 511;
      const int hh = ocr >> 6, dd = ocr & 63;
      const int f = (dd << 3) + m;
      if (region == 0) {
        size_t base = (size_t)hh * 4096 * 512 + f;
#pragma unroll
        for (int r = 0; r < 4; r++)
          Qg[base + (size_t)(posb + r) * 512] = f2bf(acc[i][j][r] * QSCALE);
      } else if (region == 1) {
        size_t base = (size_t)hh * 4096 * 512 + f;
#pragma unroll
        for (int r = 0; r < 4; r++)
          Kg[base + (size_t)(posb + r) * 512] = f2bf(acc[i][j][r]);
      } else {
        short4v pk;
#pragma unroll
        for (int r = 0; r < 4; r++) pk[r] = (short)f2bf(acc[i][j][r]);
        *(short4v*)(Vg + ((size_t)hh * 512 + f) * 4096 + posb) = pk;
      }
    }
  }
}

// ---------------- K2: flash attention, 8 waves = 4 pairs x 32 q, f-split ----------
// Pair (2w, 2w+1) owns 32 q-rows. Each wave contracts its 256-f half in QK^T
// (partial S^T), exchanges partials via LDS (80-B lane rows, conflict-free),
// adds, then P=exp2(S) in-reg (cvt_pk+permlane, R5-verified math) and PV over
// its 8 f-tiles. q[16]=64 + o[8]=128 VGPR -> fits 256, 2 waves/SIMD.
__global__ __launch_bounds__(512, 2)
void k_attn(const unsigned short* __restrict__ Qg,
            const unsigned short* __restrict__ Kg,
            const unsigned short* __restrict__ Vg,
            unsigned short* __restrict__ AO) {
  // Kt [0,32K) | Vt [32K,64K) | Sx [64K,104K) 8w x 64lane x 80B | Ls 512B
  __shared__ __align__(16) char lds[107008];
  char* Kt = lds;
  char* Vt = lds + 32768;
  char* Sx = lds + 65536;
  float* Ls = (float*)(lds + 106496);

  const int tid = threadIdx.x;
  const int lane = tid & 63, w = tid >> 6;
  const int l31 = lane & 31, hi = lane >> 5;
  const int wpair = w >> 1, whalf = w & 1;
  const int h = blockIdx.y;
  const int qbase = blockIdx.x * 128 + wpair * 32;
  const int fh = whalf << 8;  // 0 or 256

  const size_t kb = (size_t)h * 4096 * 512;
  const size_t vb = (size_t)h * 512 * 4096;

  // Q B-frags for this wave's f-half: Q[q=qbase+l31][fh + ks*16 + hi*8 + j]
  short8 q[16];
  {
    const unsigned short* qp =
        Qg + ((size_t)h * 4096 + qbase + l31) * 512 + fh + hi * 8;
#pragma unroll
    for (int ks = 0; ks < 16; ks++) q[ks] = *(const short8*)(qp + ks * 16);
  }

  f32x16 o[8];
#pragma unroll
  for (int t = 0; t < 8; t++)
#pragma unroll
    for (int e = 0; e < 16; e++) o[t][e] = 0.f;
  float lacc = 0.f;

  // PV read constants (R5-verified)
  const int rb = l31 >> 1;
  const int swz = rb & 7;
  const int cg0 = ((l31 & 1) << 2) + hi;
  const int voff1 = rb * 128 + ((cg0 ^ swz) << 4);
  const int voff2 = rb * 128 + (((cg0 + 2) ^ swz) << 4);

  char* sxw = Sx + w * 5120 + lane * 80;
  char* sxp = Sx + (w ^ 1) * 5120 + lane * 80;

  union U { uint32_t d[4]; short8 s; };

  for (int it = 0; it < 128; it++) {
    const int key0 = it << 5;
    __syncthreads();  // B0: K/V/Sx safe to overwrite
#pragma unroll
    for (int i = 0; i < 4; i++) {  // K tile: 2048 16B slots
      int s = tid + (i << 9);
      int r = s >> 6, c = s & 63;
      gl_lds16(Kg + kb + (size_t)(key0 + r) * 512 + ((c ^ r) << 3),
               Kt + (size_t)s * 16);
    }
#pragma unroll
    for (int i = 0; i < 4; i++) {  // V^T tile: 2048 16B slots
      int s = tid + (i << 9);
      int rp = s >> 3, c = s & 7;
      int cu = c ^ (rp & 7);
      int f = (rp << 1) + (cu >> 2);
      gl_lds16(Vg + vb + (size_t)f * 4096 + key0 + ((cu & 3) << 3),
               Vt + (size_t)s * 16);
    }
    __syncthreads();  // B1: tiles ready

    // partial S^T over this wave's 256-f half
    f32x16 st;
#pragma unroll
    for (int e = 0; e < 16; e++) st[e] = 0.f;
#pragma unroll
    for (int ks = 0; ks < 16; ks++) {
      int ch = ((fh >> 3) + (ks << 1) + hi) ^ l31;
      short8 kfrag = *(const short8*)(Kt + (l31 << 10) + (ch << 4));
      st = mfma32(kfrag, q[ks], st);
    }
    // write partial to Sx
#pragma unroll
    for (int j = 0; j < 4; j++) {
      f32x4 pw = (f32x4){st[4 * j], st[4 * j + 1], st[4 * j + 2], st[4 * j + 3]};
      *(f32x4*)(sxw + j * 16) = pw;
    }
    __syncthreads();  // B2: partials visible
#pragma unroll
    for (int j = 0; j < 4; j++) {
      f32x4 pv = *(const f32x4*)(sxp + j * 16);
      st[4 * j] += pv[0]; st[4 * j + 1] += pv[1];
      st[4 * j + 2] += pv[2]; st[4 * j + 3] += pv[3];
    }

    // P = exp2(S) (fixed-reference softmax; log2e folded into Q)
    float p[16];
#pragma unroll
    for (int r = 0; r < 16; r++) p[r] = __builtin_amdgcn_exp2f(st[r]);
    lacc += ((p[0] + p[1]) + (p[2] + p[3])) + ((p[4] + p[5]) + (p[6] + p[7])) +
            (((p[8] + p[9]) + (p[10] + p[11])) +
             ((p[12] + p[13]) + (p[14] + p[15])));

    // pack -> PV A-frags (lane: row=q=l31, k=8*hi+j), R5-verified
    uint32_t d0 = cvtpk(p[0], p[1]),  d1 = cvtpk(p[2], p[3]);
    uint32_t d2 = cvtpk(p[4], p[5]),  d3 = cvtpk(p[6], p[7]);
    uint32_t d4 = cvtpk(p[8], p[9]),  d5 = cvtpk(p[10], p[11]);
    uint32_t d6 = cvtpk(p[12], p[13]), d7 = cvtpk(p[14], p[15]);
    plswap(d0, d2); plswap(d1, d3);  // keys 0..15
    plswap(d4, d6); plswap(d5, d7);  // keys 16..31
    U u1; u1.d[0] = d0; u1.d[1] = d1; u1.d[2] = d2; u1.d[3] = d3;
    U u2; u2.d[0] = d4; u2.d[1] = d5; u2.d[2] = d6; u2.d[3] = d7;

    // O += P · V over this wave's 8 f-tiles
#pragma unroll
    for (int tt = 0; tt < 8; tt++) {
      const char* vrow = Vt + (((whalf << 3) + tt) << 11);
      short8 v1 = *(const short8*)(vrow + voff1);
      short8 v2 = *(const short8*)(vrow + voff2);
      o[tt] = mfma32(u1.s, v1, o[tt]);
      o[tt] = mfma32(u2.s, v2, o[tt]);
    }
  }

  lacc += __shfl_xor(lacc, 32, 64);
  if (whalf == 0) Ls[(wpair << 5) + l31] = lacc;
  __syncthreads();

  float linv[16];
#pragma unroll
  for (int r = 0; r < 16; r++) {
    int qq = (r & 3) + ((r >> 2) << 3) + (hi << 2);
    linv[r] = 1.f / Ls[(wpair << 5) + qq];
  }
#pragma unroll
  for (int tt = 0; tt < 8; tt++) {
    size_t col = (size_t)h * 512 + (((whalf << 3) + tt) << 5) + l31;
#pragma unroll
    for (int r = 0; r < 16; r++) {
      int qq = qbase + (r & 3) + ((r >> 2) << 3) + (hi << 2);
      AO[(size_t)qq * 4096 + col] = f2bf(o[tt][r] * linv[r]);
    }
  }
}

// ---------------- K3: out conv, A staged once + 5 shifted taps ----------------
// Per 32-feat step: stage A [136 rows][32f] (80B rows) + B [5t][128 oc][32f]
// (80B rows); inner loop t=0..4 reuses the A tile at row offset +t.
// Fetch/block: A 1.1 MB + B 5.1 MB (vs 10.2 MB im2col).
__global__ __launch_bounds__(256, 2)
void k_outconv(const unsigned short* __restrict__ AO,
               const unsigned short* __restrict__ WB,
               float* __restrict__ outp, int b) {
  __shared__ __align__(16) char Lc[62080];  // A: 680 slots | B: 3200 slots
  const int tid = threadIdx.x;
  const int lane = tid & 63, w = tid >> 6;
  const int wr = w >> 1, wc = w & 1;
  const int l15 = lane & 15, lg = lane >> 4;
  const int i0 = blockIdx.x * 128;
  const int ocb = blockIdx.y * 128;

  f32x4 acc[4][4];
#pragma unroll
  for (int i = 0; i < 4; i++)
#pragma unroll
    for (int j = 0; j < 4; j++) acc[i][j] = (f32x4){0.f, 0.f, 0.f, 0.f};

  // Precompute per-thread staging source offsets (sans f0); constant-indexed.
  size_t soff[16];
  bool sact[16];
#pragma unroll
  for (int i = 0; i < 16; i++) {
    int s = tid + (i << 8);
    sact[i] = (s < 3880);
    int sc = sact[i] ? s : 0;
    size_t off;
    if (sc < 680) {
      int r = sc / 5, c = sc - r * 5;
      int cr = c < 4 ? c : 3;
      off = (size_t)refl4096(i0 + r - 2) * 4096 + ((cr ^ (r & 3)) << 3);
    } else {
      int sB = sc - 680;
      int t = sB / 640;
      int rem = sB - t * 640;
      int row = rem / 5, c = rem - row * 5;
      int cr = c < 4 ? c : 3;
      off = 0x80000000u + (size_t)(ocb + row) * 20480 + t * 4096 +
            ((cr ^ (row & 3)) << 3);
    }
    soff[i] = off;
  }

  for (int step = 0; step < 128; step++) {
    const int f0 = step << 5;
    __syncthreads();
#pragma unroll
    for (int i = 0; i < 16; i++) {
      if (sact[i]) {
        int s = tid + (i << 8);
        size_t off = soff[i];
        const unsigned short* src =
            (off & 0x80000000u) ? (WB + (off & 0x7fffffffu) + f0)
                                : (AO + off + f0);
        gl_lds16(src, Lc + (size_t)s * 16);
      }
    }
    __syncthreads();
#pragma unroll
    for (int t = 0; t < 5; t++) {
      short8 af[4], bq[4];
#pragma unroll
      for (int i = 0; i < 4; i++) {
        int r = (wr << 6) + (i << 4) + l15 + t;
        af[i] = *(const short8*)(Lc + r * 80 + ((lg ^ (r & 3)) << 4));
      }
#pragma unroll
      for (int j = 0; j < 4; j++) {
        int rq = (wc << 6) + (j << 4) + l15;
        bq[j] = *(const short8*)(Lc + 10880 + t * 10240 + rq * 80 +
                                 ((lg ^ (rq & 3)) << 4));
      }
#pragma unroll
      for (int i = 0; i < 4; i++)
#pragma unroll
        for (int j = 0; j < 4; j++) acc[i][j] = mfma16(af[i], bq[j], acc[i][j]);
    }
  }
#pragma unroll
  for (int i = 0; i < 4; i++)
#pragma unroll
    for (int j = 0; j < 4; j++) {
      int oc = ocb + (wc << 6) + (j << 4) + l15;
      int pos = i0 + (wr << 6) + (i << 4) + (lg << 2);
      *(f32x4*)(outp + ((size_t)b * 1024 + oc) * 4096 + pos) = acc[i][j];
    }
}

// ---------------- launch ----------------
extern "C" void kernel_launch(void* const* d_in, const int* in_sizes, int n_in,
                              void* d_out, int out_size, void* d_ws,
                              size_t ws_size, hipStream_t stream) {
  const float* x = (const float*)d_in[0];
  const float* Wq = (const float*)d_in[1];
  const float* Wkv = (const float*)d_in[2];
  const float* Wout = (const float*)d_in[3];
  float* out = (float*)d_out;
  char* ws = (char*)d_ws;

  const size_t SEG = 33554432;  // 32 MiB
  unsigned short* Qg = (unsigned short*)ws;
  unsigned short* Kg = (unsigned short*)(ws + SEG);
  unsigned short* Vg = (unsigned short*)(ws + 2 * SEG);
  unsigned short* AO = (unsigned short*)(ws + 3 * SEG);
  unsigned short* WB1 = (unsigned short*)(ws + 4 * SEG);  // 1.97 MB
  unsigned short* WB2 = (unsigned short*)ws;  // overlays Qg/Kg during k_outconv

  k_convw_qkv<<<3840, 256, 0, stream>>>(Wq, Wkv, WB1);
  for (int b = 0; b < 2; b++) {
    k_qkv<<<dim3(32, 12, 8), 256, 0, stream>>>(x, WB1, Qg, Kg, Vg, b);
    k_attn<<<dim3(32, 8), 512, 0, stream>>>(Qg, Kg, Vg, AO);
    k_convw_out<<<1024, 256, 0, stream>>>(Wout, WB2);
    k_outconv<<<dim3(32, 8), 256, 0, stream>>>(AO, WB2, out, b);
  }
}

// Round 7
// 1567.624 us; speedup vs baseline: 2.8166x; 1.0645x over previous
//
#include <hip/hip_runtime.h>
#include <stdint.h>

// Seq_CNN_Big_Attention: qkv 1x5 conv (reflect pad) -> flash attn (head dim 512)
// -> 8x5 out conv. bf16 MFMA pipeline, per-batch sequential to bound ws.
// R7: k_attn: post-B2 prefetch (K single-buf WAR-safe, V double-buf) -> staging
//     fully hidden, 2 barriers/iter. k_outconv: (M,N)=(256,64) fetch-optimal
//     tile (1.18 GB vs 1.6 GB), 512 thr.
// Workspace (needs 136.2 MB):
//   [0,32M)    Qg bf16 [8][4096][512]  (f = d*8+m, pre-scaled 0.125*log2e)
//   [32M,64M)  Kg bf16 [8][4096][512]
//   [64M,96M)  Vg bf16 [8][512][4096]  (transposed for PV B-frags)
//   [96M,128M) AO bf16 [4096][4096]    (feat = ic*8+mi)
//   [128M,130M) WB1 bf16 [1536][640]   (qkv weights, k = t*128+ci)
//   WB2 bf16 [1024][20480] overlays Qg/Kg during k_outconv (reconverted per b)

typedef __attribute__((ext_vector_type(8))) short short8;
typedef __attribute__((ext_vector_type(4))) short short4v;
typedef __attribute__((ext_vector_type(2))) short short2v;
typedef __attribute__((ext_vector_type(4))) float f32x4;
typedef __attribute__((ext_vector_type(16))) float f32x16;

__device__ __forceinline__ f32x4 mfma16(short8 a, short8 b, f32x4 c) {
  return __builtin_amdgcn_mfma_f32_16x16x32_bf16(a, b, c, 0, 0, 0);
}
__device__ __forceinline__ f32x16 mfma32(short8 a, short8 b, f32x16 c) {
  return __builtin_amdgcn_mfma_f32_32x32x16_bf16(a, b, c, 0, 0, 0);
}

__device__ __forceinline__ unsigned short f2bf(float f) {  // RNE f32->bf16
  union { float f; uint32_t u; } v; v.f = f;
  uint32_t r = (v.u + 0x7fffu + ((v.u >> 16) & 1u)) >> 16;
  return (unsigned short)r;
}

__device__ __forceinline__ uint32_t cvtpk(float lo, float hi) {
  uint32_t r;
  asm volatile("v_cvt_pk_bf16_f32 %0, %1, %2" : "=v"(r) : "v"(lo), "v"(hi));
  return r;
}
__device__ __forceinline__ void plswap(uint32_t& a, uint32_t& b) {
  asm volatile("v_permlane32_swap_b32 %0, %1" : "+v"(a), "+v"(b));
}

__device__ __forceinline__ int refl4096(int p) {  // reflect pad-2 index
  p = p < 0 ? -p : p;
  return p >= 4096 ? 8190 - p : p;
}

__device__ __forceinline__ void gl_lds16(const void* g, void* l) {
  __builtin_amdgcn_global_load_lds(
      (const __attribute__((address_space(1))) void*)g,
      (__attribute__((address_space(3))) void*)l, 16, 0, 0);
}

// ---------------- weight converters ----------------
__global__ void k_convw_qkv(const float* __restrict__ Wq,
                            const float* __restrict__ Wkv,
                            unsigned short* __restrict__ out) {
  int e = blockIdx.x * 256 + threadIdx.x;  // 1536*640 exact
  int oc = e / 640, k = e - oc * 640;
  int ci = k & 127, t = k >> 7;
  float w = (oc < 512) ? Wq[oc * 640 + ci * 5 + t]
                       : Wkv[(oc - 512) * 640 + ci * 5 + t];
  out[e] = f2bf(w);
}

// one block per oc row: coalesced f32x4 read -> LDS bf16 -> coalesced write
__global__ __launch_bounds__(256)
void k_convw_out(const float* __restrict__ Wout,
                 unsigned short* __restrict__ out) {
  __shared__ unsigned short row_l[20480];
  const int oc = blockIdx.x;
  const int tid = threadIdx.x;
  const float* src = Wout + (size_t)oc * 20480;
#pragma unroll
  for (int i0 = 0; i0 < 5120; i0 += 256) {  // 20 rounds of f32x4
    int i = i0 + tid;
    f32x4 v = *(const f32x4*)(src + (size_t)i * 4);
    short4v pk;
    pk[0] = (short)f2bf(v[0]); pk[1] = (short)f2bf(v[1]);
    pk[2] = (short)f2bf(v[2]); pk[3] = (short)f2bf(v[3]);
    *(short4v*)(row_l + i * 4) = pk;
  }
  __syncthreads();
  unsigned short* drow = out + (size_t)oc * 20480;
#pragma unroll
  for (int r0 = 0; r0 < 20480; r0 += 512) {  // 40 rounds of ushort2
    int e = r0 + tid * 2;
    int t0 = e >> 12, ft0 = e & 4095;
    int t1 = (e + 1) >> 12, ft1 = (e + 1) & 4095;
    short2v pk;
    pk[0] = (short)row_l[(ft0 >> 3) * 40 + (ft0 & 7) * 5 + t0];
    pk[1] = (short)row_l[(ft1 >> 3) * 40 + (ft1 & 7) * 5 + t1];
    *(short2v*)(drow + e) = pk;
  }
}

// ---------------- K1: qkv conv as GEMM (M=128pos x N=128oc, K=640) ----------------
__global__ __launch_bounds__(256, 2)
void k_qkv(const float* __restrict__ x, const unsigned short* __restrict__ Wb,
           unsigned short* __restrict__ Qg, unsigned short* __restrict__ Kg,
           unsigned short* __restrict__ Vg, int b) {
  __shared__ __align__(16) unsigned short As[128 * 64];
  __shared__ __align__(16) unsigned short Bs[128 * 64];
  const int tid = threadIdx.x;
  const int lane = tid & 63, w = tid >> 6;
  const int wr = w >> 1, wc = w & 1;
  const int l15 = lane & 15, lg = lane >> 4;
  const int p0 = blockIdx.x * 128;
  const int ocb = blockIdx.y * 128;
  const int m = blockIdx.z;

  f32x4 acc[4][4];
#pragma unroll
  for (int i = 0; i < 4; i++)
#pragma unroll
    for (int j = 0; j < 4; j++) acc[i][j] = (f32x4){0.f, 0.f, 0.f, 0.f};

  for (int ks = 0; ks < 10; ks++) {
    const int t = ks >> 1;
    const int ci0 = (ks & 1) << 6;
    __syncthreads();
#pragma unroll
    for (int rr = 0; rr < 8; rr++) {
      int slot = tid + (rr << 8);
      int row = slot >> 4, c4 = slot & 15;
      int xn = refl4096(p0 + row - 2 + t);
      const f32x4 v = *(const f32x4*)(x + ((size_t)b * 4096 + xn) * 1024 +
                                      m * 128 + ci0 + (c4 << 2));
      short4v pk;
      pk[0] = (short)f2bf(v[0]); pk[1] = (short)f2bf(v[1]);
      pk[2] = (short)f2bf(v[2]); pk[3] = (short)f2bf(v[3]);
      int byte = (row << 7) + ((((c4 >> 1) ^ (row & 7))) << 4) + ((c4 & 1) << 3);
      *(short4v*)((char*)As + byte) = pk;
    }
#pragma unroll
    for (int c = 0; c < 4; c++) {
      int sb = ((c << 2) + w) << 6;
      int slot = sb + lane;
      int row = slot >> 3, cc = slot & 7;
      int cs = cc ^ (row & 7);
      gl_lds16(Wb + (size_t)(ocb + row) * 640 + (ks << 6) + (cs << 3),
               (char*)Bs + (size_t)sb * 16);
    }
    __syncthreads();
#pragma unroll
    for (int kk = 0; kk < 2; kk++) {
      short8 af[4], bq[4];
#pragma unroll
      for (int i = 0; i < 4; i++) {
        int row = (wr << 6) + (i << 4) + l15;
        af[i] = *(const short8*)((char*)As + (row << 7) +
                                 ((((kk << 2) + lg) ^ (row & 7)) << 4));
      }
#pragma unroll
      for (int j = 0; j < 4; j++) {
        int row = (wc << 6) + (j << 4) + l15;
        bq[j] = *(const short8*)((char*)Bs + (row << 7) +
                                 ((((kk << 2) + lg) ^ (row & 7)) << 4));
      }
#pragma unroll
      for (int i = 0; i < 4; i++)
#pragma unroll
        for (int j = 0; j < 4; j++) acc[i][j] = mfma16(af[i], bq[j], acc[i][j]);
    }
  }

  const int region = ocb >> 9;  // 0:Q 1:K 2:V
  const float QSCALE = 0.18033688f;  // 1/8 * log2(e)
#pragma unroll
  for (int i = 0; i < 4; i++) {
    const int posb = p0 + (wr << 6) + (i << 4) + (lg << 2);
#pragma unroll
    for (int j = 0; j < 4; j++) {
      const int oc = ocb + (wc << 6) + (j << 4) + l15;
      const int ocr = oc & 511;
      const int hh = ocr >> 6, dd = ocr & 63;
      const int f = (dd << 3) + m;
      if (region == 0) {
        size_t base = (size_t)hh * 4096 * 512 + f;
#pragma unroll
        for (int r = 0; r < 4; r++)
          Qg[base + (size_t)(posb + r) * 512] = f2bf(acc[i][j][r] * QSCALE);
      } else if (region == 1) {
        size_t base = (size_t)hh * 4096 * 512 + f;
#pragma unroll
        for (int r = 0; r < 4; r++)
          Kg[base + (size_t)(posb + r) * 512] = f2bf(acc[i][j][r]);
      } else {
        short4v pk;
#pragma unroll
        for (int r = 0; r < 4; r++) pk[r] = (short)f2bf(acc[i][j][r]);
        *(short4v*)(Vg + ((size_t)hh * 512 + f) * 4096 + posb) = pk;
      }
    }
  }
}

// ---------------- K2: flash attention, 8 waves = 4 pairs x 32 q, f-split ----------
// R6 math; R7 schedule: per iter
//   B1 (__syncthreads: drains prev-issued stage loads) -> QK^T partial (Kt)
//   -> Sx write -> B2 -> [issue stage K(t+1)->Kt, V(t+1)->Vt^1]  (WAR-safe:
//   all Kt reads done at B2; Vt^1 reads done before B1) -> exchange add,
//   exp, pack, PV (Vt cur). Staging hides under ~3000 cyc of tail compute.
__global__ __launch_bounds__(512, 2)
void k_attn(const unsigned short* __restrict__ Qg,
            const unsigned short* __restrict__ Kg,
            const unsigned short* __restrict__ Vg,
            unsigned short* __restrict__ AO) {
  // Kt [0,32K) | Vt0 [32K,64K) | Vt1 [64K,96K) | Sx [96K,136K) | Ls 512B
  __shared__ __align__(16) char lds[139776];
  char* Kt = lds;
  char* Vt0 = lds + 32768;
  char* Vt1 = lds + 65536;
  char* Sx = lds + 98304;
  float* Ls = (float*)(lds + 139264);

  const int tid = threadIdx.x;
  const int lane = tid & 63, w = tid >> 6;
  const int l31 = lane & 31, hi = lane >> 5;
  const int wpair = w >> 1, whalf = w & 1;
  const int h = blockIdx.y;
  const int qbase = blockIdx.x * 128 + wpair * 32;
  const int fh = whalf << 8;  // 0 or 256

  const size_t kb = (size_t)h * 4096 * 512;
  const size_t vb = (size_t)h * 512 * 4096;

  // Q B-frags for this wave's f-half: Q[q=qbase+l31][fh + ks*16 + hi*8 + j]
  short8 q[16];
  {
    const unsigned short* qp =
        Qg + ((size_t)h * 4096 + qbase + l31) * 512 + fh + hi * 8;
#pragma unroll
    for (int ks = 0; ks < 16; ks++) q[ks] = *(const short8*)(qp + ks * 16);
  }

  f32x16 o[8];
#pragma unroll
  for (int t = 0; t < 8; t++)
#pragma unroll
    for (int e = 0; e < 16; e++) o[t][e] = 0.f;
  float lacc = 0.f;

  // PV read constants (R5-verified)
  const int rb = l31 >> 1;
  const int swz = rb & 7;
  const int cg0 = ((l31 & 1) << 2) + hi;
  const int voff1 = rb * 128 + ((cg0 ^ swz) << 4);
  const int voff2 = rb * 128 + (((cg0 + 2) ^ swz) << 4);

  char* sxw = Sx + w * 5120 + lane * 80;
  char* sxp = Sx + (w ^ 1) * 5120 + lane * 80;

  union U { uint32_t d[4]; short8 s; };

  auto stageK = [&](int it) {
    const int key0 = it << 5;
#pragma unroll
    for (int i = 0; i < 4; i++) {  // 2048 16B slots
      int s = tid + (i << 9);
      int r = s >> 6, c = s & 63;
      gl_lds16(Kg + kb + (size_t)(key0 + r) * 512 + ((c ^ r) << 3),
               Kt + (size_t)s * 16);
    }
  };
  auto stageV = [&](int it, char* Vt) {
    const int key0 = it << 5;
#pragma unroll
    for (int i = 0; i < 4; i++) {  // 2048 16B slots
      int s = tid + (i << 9);
      int rp = s >> 3, c = s & 7;
      int cu = c ^ (rp & 7);
      int f = (rp << 1) + (cu >> 2);
      gl_lds16(Vg + vb + (size_t)f * 4096 + key0 + ((cu & 3) << 3),
               Vt + (size_t)s * 16);
    }
  };

  stageK(0);
  stageV(0, Vt0);

  for (int it = 0; it < 128; it++) {
    char* Vt = (it & 1) ? Vt1 : Vt0;
    char* Vn = (it & 1) ? Vt0 : Vt1;
    __syncthreads();  // B1: staged tiles landed (per-wave vmcnt drain + barrier)

    // partial S^T over this wave's 256-f half
    f32x16 st;
#pragma unroll
    for (int e = 0; e < 16; e++) st[e] = 0.f;
#pragma unroll
    for (int ks = 0; ks < 16; ks++) {
      int ch = ((fh >> 3) + (ks << 1) + hi) ^ l31;
      short8 kfrag = *(const short8*)(Kt + (l31 << 10) + (ch << 4));
      st = mfma32(kfrag, q[ks], st);
    }
    // write partial to Sx
#pragma unroll
    for (int j = 0; j < 4; j++) {
      f32x4 pw = (f32x4){st[4 * j], st[4 * j + 1], st[4 * j + 2], st[4 * j + 3]};
      *(f32x4*)(sxw + j * 16) = pw;
    }
    __syncthreads();  // B2: Kt reads done, partials visible

    // prefetch next tiles; they fly under the whole tail of this iter
    if (it < 127) {
      stageK(it + 1);
      stageV(it + 1, Vn);
    }

#pragma unroll
    for (int j = 0; j < 4; j++) {
      f32x4 pv = *(const f32x4*)(sxp + j * 16);
      st[4 * j] += pv[0]; st[4 * j + 1] += pv[1];
      st[4 * j + 2] += pv[2]; st[4 * j + 3] += pv[3];
    }

    // P = exp2(S) (fixed-reference softmax; log2e folded into Q)
    float p[16];
#pragma unroll
    for (int r = 0; r < 16; r++) p[r] = __builtin_amdgcn_exp2f(st[r]);
    lacc += ((p[0] + p[1]) + (p[2] + p[3])) + ((p[4] + p[5]) + (p[6] + p[7])) +
            (((p[8] + p[9]) + (p[10] + p[11])) +
             ((p[12] + p[13]) + (p[14] + p[15])));

    // pack -> PV A-frags (lane: row=q=l31, k=8*hi+j), R5-verified
    uint32_t d0 = cvtpk(p[0], p[1]),  d1 = cvtpk(p[2], p[3]);
    uint32_t d2 = cvtpk(p[4], p[5]),  d3 = cvtpk(p[6], p[7]);
    uint32_t d4 = cvtpk(p[8], p[9]),  d5 = cvtpk(p[10], p[11]);
    uint32_t d6 = cvtpk(p[12], p[13]), d7 = cvtpk(p[14], p[15]);
    plswap(d0, d2); plswap(d1, d3);  // keys 0..15
    plswap(d4, d6); plswap(d5, d7);  // keys 16..31
    U u1; u1.d[0] = d0; u1.d[1] = d1; u1.d[2] = d2; u1.d[3] = d3;
    U u2; u2.d[0] = d4; u2.d[1] = d5; u2.d[2] = d6; u2.d[3] = d7;

    // O += P · V over this wave's 8 f-tiles
#pragma unroll
    for (int tt = 0; tt < 8; tt++) {
      const char* vrow = Vt + (((whalf << 3) + tt) << 11);
      short8 v1 = *(const short8*)(vrow + voff1);
      short8 v2 = *(const short8*)(vrow + voff2);
      o[tt] = mfma32(u1.s, v1, o[tt]);
      o[tt] = mfma32(u2.s, v2, o[tt]);
    }
  }

  lacc += __shfl_xor(lacc, 32, 64);
  if (whalf == 0) Ls[(wpair << 5) + l31] = lacc;
  __syncthreads();

  float linv[16];
#pragma unroll
  for (int r = 0; r < 16; r++) {
    int qq = (r & 3) + ((r >> 2) << 3) + (hi << 2);
    linv[r] = 1.f / Ls[(wpair << 5) + qq];
  }
#pragma unroll
  for (int tt = 0; tt < 8; tt++) {
    size_t col = (size_t)h * 512 + (((whalf << 3) + tt) << 5) + l31;
#pragma unroll
    for (int r = 0; r < 16; r++) {
      int qq = qbase + (r & 3) + ((r >> 2) << 3) + (hi << 2);
      AO[(size_t)qq * 4096 + col] = f2bf(o[tt][r] * linv[r]);
    }
  }
}

// ---------------- K3: out conv, M=256 x N=64, A staged once + 5 shifted taps ----
// Fetch-optimal: total = 32MB*(1024/64) + 42MB*(4096/256) = 1.18 GB (was 1.6).
// 512 thr, 8 waves (4 M-bands x 2 N-bands), wave tile 64x32. LDS 46.7 KB.
__global__ __launch_bounds__(512, 2)
void k_outconv(const unsigned short* __restrict__ AO,
               const unsigned short* __restrict__ WB,
               float* __restrict__ outp, int b) {
  __shared__ __align__(16) char Lc[46720];  // A: 1300 slots | B: 1600 slots
  const int tid = threadIdx.x;
  const int lane = tid & 63, w = tid >> 6;
  const int wr = w >> 1, wc = w & 1;
  const int l15 = lane & 15, lg = lane >> 4;
  const int i0 = blockIdx.x * 256;
  const int ocb = blockIdx.y * 64;

  f32x4 acc[4][2];
#pragma unroll
  for (int i = 0; i < 4; i++)
#pragma unroll
    for (int j = 0; j < 2; j++) acc[i][j] = (f32x4){0.f, 0.f, 0.f, 0.f};

  // Precompute per-thread staging source offsets (sans f0); constant-indexed.
  size_t soff[6];
  bool sact[6];
#pragma unroll
  for (int i = 0; i < 6; i++) {
    int s = tid + (i << 9);
    sact[i] = (s < 2900);
    int sc = sact[i] ? s : 0;
    size_t off;
    if (sc < 1300) {  // A: 260 rows x 5 chunks (80B rows, chunk^=(row&3))
      int r = sc / 5, c = sc - r * 5;
      int cr = c < 4 ? c : 3;
      off = (size_t)refl4096(i0 + r - 2) * 4096 + ((cr ^ (r & 3)) << 3);
    } else {  // B: 320 rows (t*64+oc) x 5 chunks
      int sB = sc - 1300;
      int row = sB / 5, c = sB - row * 5;
      int cr = c < 4 ? c : 3;
      int t = row >> 6, qoc = row & 63;
      off = 0x80000000u + (size_t)(ocb + qoc) * 20480 + t * 4096 +
            ((cr ^ (row & 3)) << 3);
    }
    soff[i] = off;
  }

  for (int step = 0; step < 128; step++) {
    const int f0 = step << 5;
    __syncthreads();
#pragma unroll
    for (int i = 0; i < 6; i++) {
      if (sact[i]) {
        int s = tid + (i << 9);
        size_t off = soff[i];
        const unsigned short* src =
            (off & 0x80000000u) ? (WB + (off & 0x7fffffffu) + f0)
                                : (AO + off + f0);
        gl_lds16(src, Lc + (size_t)s * 16);
      }
    }
    __syncthreads();
#pragma unroll
    for (int t = 0; t < 5; t++) {
      short8 af[4], bq[2];
#pragma unroll
      for (int i = 0; i < 4; i++) {
        int r = (wr << 6) + (i << 4) + l15 + t;
        af[i] = *(const short8*)(Lc + r * 80 + ((lg ^ (r & 3)) << 4));
      }
#pragma unroll
      for (int j = 0; j < 2; j++) {
        int rowb = (t << 6) + (wc << 5) + (j << 4) + l15;
        bq[j] = *(const short8*)(Lc + 20800 + rowb * 80 +
                                 ((lg ^ (rowb & 3)) << 4));
      }
#pragma unroll
      for (int i = 0; i < 4; i++)
#pragma unroll
        for (int j = 0; j < 2; j++) acc[i][j] = mfma16(af[i], bq[j], acc[i][j]);
    }
  }
#pragma unroll
  for (int i = 0; i < 4; i++)
#pragma unroll
    for (int j = 0; j < 2; j++) {
      int oc = ocb + (wc << 5) + (j << 4) + l15;
      int pos = i0 + (wr << 6) + (i << 4) + (lg << 2);
      *(f32x4*)(outp + ((size_t)b * 1024 + oc) * 4096 + pos) = acc[i][j];
    }
}

// ---------------- launch ----------------
extern "C" void kernel_launch(void* const* d_in, const int* in_sizes, int n_in,
                              void* d_out, int out_size, void* d_ws,
                              size_t ws_size, hipStream_t stream) {
  const float* x = (const float*)d_in[0];
  const float* Wq = (const float*)d_in[1];
  const float* Wkv = (const float*)d_in[2];
  const float* Wout = (const float*)d_in[3];
  float* out = (float*)d_out;
  char* ws = (char*)d_ws;

  const size_t SEG = 33554432;  // 32 MiB
  unsigned short* Qg = (unsigned short*)ws;
  unsigned short* Kg = (unsigned short*)(ws + SEG);
  unsigned short* Vg = (unsigned short*)(ws + 2 * SEG);
  unsigned short* AO = (unsigned short*)(ws + 3 * SEG);
  unsigned short* WB1 = (unsigned short*)(ws + 4 * SEG);  // 1.97 MB
  unsigned short* WB2 = (unsigned short*)ws;  // overlays Qg/Kg during k_outconv

  k_convw_qkv<<<3840, 256, 0, stream>>>(Wq, Wkv, WB1);
  for (int b = 0; b < 2; b++) {
    k_qkv<<<dim3(32, 12, 8), 256, 0, stream>>>(x, WB1, Qg, Kg, Vg, b);
    k_attn<<<dim3(32, 8), 512, 0, stream>>>(Qg, Kg, Vg, AO);
    k_convw_out<<<1024, 256, 0, stream>>>(Wout, WB2);
    k_outconv<<<dim3(16, 16), 512, 0, stream>>>(AO, WB2, out, b);
  }
}